// Round 6
// baseline (287.984 us; speedup 1.0000x reference)
//
#include <hip/hip_runtime.h>

#define DIM 768
#define NHEADS 12
#define HDIM 64
#define BATCH 8
#define LQ 1024
#define LKV 1024
#define ATTN_SCALE 0.125f
#define LOG2E 1.4426950408889634f
// ATTN_SCALE * LOG2E, pre-applied to Q in proj_gemm's epilogue.
#define C1_SL2E 0.18033688011112042f

typedef __bf16 bf16;
typedef __bf16 bf16x4 __attribute__((ext_vector_type(4)));
typedef __bf16 bf16x8 __attribute__((ext_vector_type(8)));
typedef short s16x4 __attribute__((ext_vector_type(4)));
typedef float f32x4 __attribute__((ext_vector_type(4)));

union B4 { bf16x4 h; s16x4 s; };

static __device__ __forceinline__ f32x4 mfma_k32(bf16x8 a, bf16x8 b, f32x4 c) {
    return __builtin_amdgcn_mfma_f32_16x16x32_bf16(a, b, c, 0, 0, 0);
}
static __device__ __forceinline__ f32x4 mfma_k16(s16x4 a, s16x4 b, f32x4 c) {
    return __builtin_amdgcn_mfma_f32_16x16x16bf16_1k(a, b, c, 0, 0, 0);
}

static __device__ __forceinline__ void async16(const bf16* g, bf16* l) {
    __builtin_amdgcn_global_load_lds(
        (const __attribute__((address_space(1))) unsigned int*)g,
        (__attribute__((address_space(3))) unsigned int*)l, 16, 0, 0);
}
static __device__ __forceinline__ void drain_vmem() {
    __asm__ volatile("s_waitcnt vmcnt(0)" ::: "memory");
}
// counted wait: leave the newest N vmem ops (pos prefetch) in flight
#define WAIT_VMCNT(N) __asm__ volatile("s_waitcnt vmcnt(" #N ")" ::: "memory")
// keep following LDS reads from hoisting above the barrier (rule #18-adjacent)
static __device__ __forceinline__ void code_fence() {
    __asm__ volatile("" ::: "memory");
}

// ---------------- single fused fp32 -> bf16 convert ----------------
#define NQ4 (BATCH * LQ * DIM / 4)
#define NW4 (DIM * DIM / 4)
__global__ void cvt_all(const float4* __restrict__ q, const float4* __restrict__ kv,
                        const float4* __restrict__ Wq, const float4* __restrict__ Wkv,
                        const float4* __restrict__ Wp,
                        bf16x4* __restrict__ qb, bf16x4* __restrict__ kvb,
                        bf16x4* __restrict__ wall, bf16x4* __restrict__ wpb) {
    int i = blockIdx.x * 256 + threadIdx.x;
    const float4* src; bf16x4* dst; int j;
    if (i < NQ4)                { src = q;   dst = qb;        j = i; }
    else if (i < 2 * NQ4)       { src = kv;  dst = kvb;       j = i - NQ4; }
    else if (i < 2 * NQ4 + NW4) { src = Wq;  dst = wall;      j = i - 2 * NQ4; }
    else if (i < 2 * NQ4 + 3 * NW4) { src = Wkv; dst = wall + NW4; j = i - 2 * NQ4 - NW4; }
    else if (i < 2 * NQ4 + 4 * NW4) { src = Wp;  dst = wpb;   j = i - 2 * NQ4 - 3 * NW4; }
    else return;
    float4 v = src[j];
    bf16x4 o;
    o[0] = (bf16)v.x; o[1] = (bf16)v.y; o[2] = (bf16)v.z; o[3] = (bf16)v.w;
    dst[j] = o;
}

// ---------------- fused projection GEMM (round-2 proven serial structure) ----------------
// Q output is pre-scaled by ATTN_SCALE*LOG2E so the attn softmax exponent is a
// single fma: e = fmaf(pos, LOG2E, s_prescaled).
__global__ __launch_bounds__(256) void proj_gemm(
    const bf16* __restrict__ qb, const bf16* __restrict__ kvb,
    const bf16* __restrict__ W,
    bf16* __restrict__ Qp, bf16* __restrict__ Kp, bf16* __restrict__ Vt)
{
    __shared__ bf16 As[128 * 32];
    __shared__ bf16 Bs[128 * 32];
    const int tid  = threadIdx.x;
    const int lane = tid & 63;
    const int w    = tid >> 6;
    const int wm = (w >> 1) * 64;
    const int wn = (w & 1) * 64;
    const int m0 = blockIdx.x * 128;
    const int n0 = blockIdx.y * 128;
    const int K = DIM;
    const int lq = lane & 15;
    const int quad = lane >> 4;

    const bf16* A = (n0 < DIM) ? qb : kvb;
    const int isV = (n0 >= 2 * DIM);

    const int rl = lane >> 2;
    const int ck = (lane & 3) * 8;
    const bf16* gA = A + (size_t)(m0 + w * 32 + rl) * K + ck;
    const bf16* gB = W + (size_t)(n0 + w * 32 + rl) * K + ck;
    bf16* lA = &As[w * 1024];
    bf16* lB = &Bs[w * 1024];

    f32x4 acc[4][4] = {};

    for (int k0 = 0; k0 < K; k0 += 32) {
        async16(gA + k0,                  lA);
        async16(gA + (size_t)16 * K + k0, lA + 512);
        async16(gB + k0,                  lB);
        async16(gB + (size_t)16 * K + k0, lB + 512);
        drain_vmem();
        __syncthreads();

        bf16x8 a[4], b[4];
        #pragma unroll
        for (int i = 0; i < 4; i++)
            a[i] = *(const bf16x8*)&As[(wm + i * 16 + lq) * 32 + quad * 8];
        #pragma unroll
        for (int j = 0; j < 4; j++)
            b[j] = *(const bf16x8*)&Bs[(wn + j * 16 + lq) * 32 + quad * 8];
        if (isV) {
            #pragma unroll
            for (int i = 0; i < 4; i++)
                #pragma unroll
                for (int j = 0; j < 4; j++)
                    acc[i][j] = mfma_k32(a[i], b[j], acc[i][j]);
        } else {
            #pragma unroll
            for (int i = 0; i < 4; i++)
                #pragma unroll
                for (int j = 0; j < 4; j++)
                    acc[i][j] = mfma_k32(b[j], a[i], acc[i][j]);
        }
        __syncthreads();
    }

    if (isV) {
        const int n0v = n0 - 2 * DIM;
        #pragma unroll
        for (int i = 0; i < 4; i++) {
            const int base_m = m0 + wm + i * 16;
            const int b_idx = base_m >> 10;
            const int kvl = (base_m & 1023) + quad * 4;
            #pragma unroll
            for (int j = 0; j < 4; j++) {
                const int nl = n0v + wn + j * 16 + lq;
                const int h = nl >> 6;
                const int d = nl & 63;
                B4 pk;
                #pragma unroll
                for (int r = 0; r < 4; r++) pk.h[r] = (bf16)acc[i][j][r];
                *(s16x4*)&Vt[(((size_t)b_idx * NHEADS + h) * HDIM + d) * LKV + kvl] = pk.s;
            }
        }
    } else {
        bf16* Cb = (n0 < DIM) ? Qp : Kp;
        const float cs = (n0 < DIM) ? C1_SL2E : 1.0f;   // pre-scale Q only
        const int nb = (n0 < DIM) ? n0 : n0 - DIM;
        #pragma unroll
        for (int i = 0; i < 4; i++) {
            const size_t row = m0 + wm + i * 16 + lq;
            #pragma unroll
            for (int j = 0; j < 4; j++) {
                const int col = nb + wn + j * 16 + quad * 4;
                B4 pk;
                #pragma unroll
                for (int r = 0; r < 4; r++) pk.h[r] = (bf16)(acc[i][j][r] * cs);
                *(s16x4*)&Cb[row * DIM + col] = pk.s;
            }
        }
    }
}

// ---------------- final GEMM: 64x128 tiles (round-2 proven serial structure) ----------------
__global__ __launch_bounds__(256) void out_gemm(
    const bf16* __restrict__ A, const bf16* __restrict__ B,
    float* __restrict__ Cp, const float* __restrict__ bias, int M, int N, int K)
{
    __shared__ bf16 As[64 * 32];
    __shared__ bf16 Bs[128 * 32];
    const int tid  = threadIdx.x;
    const int lane = tid & 63;
    const int w    = tid >> 6;
    const int wm = (w >> 1) * 32;
    const int wn = (w & 1) * 64;
    const int m0 = blockIdx.x * 64;
    const int n0 = blockIdx.y * 128;
    const int lq = lane & 15;
    const int quad = lane >> 4;

    const int rl = lane >> 2;
    const int ck = (lane & 3) * 8;
    const bf16* gA = A + (size_t)(m0 + w * 16 + rl) * K + ck;
    const bf16* gB = B + (size_t)(n0 + w * 32 + rl) * K + ck;
    bf16* lA = &As[w * 512];
    bf16* lB = &Bs[w * 1024];

    f32x4 acc[2][4] = {};

    for (int k0 = 0; k0 < K; k0 += 32) {
        async16(gA + k0,                  lA);
        async16(gB + k0,                  lB);
        async16(gB + (size_t)16 * K + k0, lB + 512);
        drain_vmem();
        __syncthreads();

        bf16x8 a[2], b[4];
        #pragma unroll
        for (int i = 0; i < 2; i++)
            a[i] = *(const bf16x8*)&As[(wm + i * 16 + lq) * 32 + quad * 8];
        #pragma unroll
        for (int j = 0; j < 4; j++)
            b[j] = *(const bf16x8*)&Bs[(wn + j * 16 + lq) * 32 + quad * 8];
        #pragma unroll
        for (int i = 0; i < 2; i++)
            #pragma unroll
            for (int j = 0; j < 4; j++)
                acc[i][j] = mfma_k32(b[j], a[i], acc[i][j]);
        __syncthreads();
    }

    #pragma unroll
    for (int i = 0; i < 2; i++) {
        const size_t row = m0 + wm + i * 16 + lq;
        #pragma unroll
        for (int j = 0; j < 4; j++) {
            const int col = n0 + wn + j * 16 + quad * 4;
            float4 bj = *(const float4*)&bias[col];
            float4 o;
            o.x = acc[i][j][0] + bj.x; o.y = acc[i][j][1] + bj.y;
            o.z = acc[i][j][2] + bj.z; o.w = acc[i][j][3] + bj.w;
            *(float4*)&Cp[row * N + col] = o;
        }
    }
}

// ---------------- fused attention ----------------
// Round-6 = round-5 content, de-risked: plain __launch_bounds__(256).
// Occupancy arithmetic (fixed from round 5): LDS 32KB/block caps at 5 blocks/CU
// = 20 waves/CU = 5 waves/SIMD, so any VGPR count <= ~102 already meets the cap;
// forcing <=64 via (256,8) risked spill for zero occupancy gain.
// Changes vs round-4 (87 us, VALU 49 / Mfma 18 / HBM 10, VGPR 80):
//  * pos prefetch depth-1 (frees ~16 VGPR): pos is L2-resident after the XCD
//    remap (FETCH halved to ~55 MB); each pA slot reloads for tile t+1 right
//    after softmax consumes it -> ~1 body (>=400 cyc) lead, enough for L2.
//  * l-sum via MFMA-ones: o_l = mfma_k16(ones, pfrag, o_l). With A==1,
//    D[m,n] = sum_k B[k][n] for any A layout; accumulates the row denominator
//    in f32 on the idle MFMA pipe, replicated over m. Removes 12 VALU adds/iter
//    and the two end shuffles; l now sums the exact bf16 P used by PV.
//  * QK/softmax interleave (QK0,QK1,SMB0,QK2,SMB1,QK3,SMB2,SMB3): sc liveness
//    16->~8 regs; exp latency hides under MFMA.
// Kept: XCD remap, raw s_barrier + vmcnt(4) (4 staging DMAs oldest, 4 pos loads
// newest -> vmcnt(4) drains exactly the DMAs; pos stays in flight across the
// barrier), setprio around MFMA clusters, source-side XOR-swizzled staging.
__global__ __launch_bounds__(256) void attn_kernel(
    const bf16* __restrict__ Qb,   // (B*LQ, 768), Q cols pre-scaled
    const bf16* __restrict__ Kb,   // (B*LKV, 768)
    const bf16* __restrict__ Vt,   // (B*H*64, LKV)
    const float* __restrict__ pos, // (H, LQ, LKV)
    bf16* __restrict__ O)          // (B*LQ, 768)
{
    __shared__ bf16 Ks[2][64 * 64];   // [buf][kv][d]  128B rows, source-swizzled
    __shared__ bf16 Vs[2][64 * 64];   // [buf][d][kv]  128B rows, source-swizzled

    const int i  = blockIdx.x;
    const int g  = (i & 7) * 24 + (i >> 6);    // (h,q0) group, XCD-resident
    const int b  = (i >> 3) & 7;
    const int h  = g >> 4;
    const int q0 = (g & 15) * 64;
    const int bh = b * NHEADS + h;
    const int t = threadIdx.x;
    const int lane = t & 63;
    const int w = t >> 6;
    const int lq = lane & 15;
    const int quad = lane >> 4;

    const bf16* qg = Qb + (size_t)(b * LQ + q0 + w * 16 + lq) * DIM + h * HDIM + quad * 8;
    bf16x8 qa0 = *(const bf16x8*)(qg);
    bf16x8 qa1 = *(const bf16x8*)(qg + 32);

    const int srow  = t >> 3;                      // 0..31
    const int chunk = t & 7;
    const int sw    = (chunk ^ (srow & 7)) * 8;    // swizzled global-source offset
    const bf16* Kg = Kb + (size_t)(b * LKV + srow) * DIM + h * HDIM + sw;
    const bf16* Vg = Vt + (size_t)(bh * HDIM + srow) * LKV + sw;

#define STAGE(kv0, bufi) do {                                                                 \
    async16(Kg + (size_t)(kv0) * DIM,        &Ks[bufi][srow * 64 + chunk * 8]);               \
    async16(Kg + (size_t)((kv0) + 32) * DIM, &Ks[bufi][(srow + 32) * 64 + chunk * 8]);        \
    async16(Vg + (kv0),                      &Vs[bufi][srow * 64 + chunk * 8]);               \
    async16(Vg + (size_t)32 * LKV + (kv0),   &Vs[bufi][(srow + 32) * 64 + chunk * 8]);        \
} while (0)

#define NT (LKV / 64)

    const float4* pos4 = (const float4*)(pos + ((size_t)h * LQ + q0 + w * 16 + lq) * LKV);

    // MFMA-ones operand: 4x bf16(1.0) = 0x3F80
    B4 onesb;
    onesb.s = (s16x4){0x3F80, 0x3F80, 0x3F80, 0x3F80};

    f32x4 o_acc[4] = {};
    f32x4 o_l = {};

    // prologue: tile0 DMA first (oldest), then pos(0) prefetch
    STAGE(0, 0);
    float4 pA0 = pos4[quad],      pA1 = pos4[4 + quad];
    float4 pA2 = pos4[8 + quad],  pA3 = pos4[12 + quad];
    WAIT_VMCNT(4);                     // DMAs done; 4 pos loads stay in flight
    __builtin_amdgcn_s_barrier();
    code_fence();

#define QK(BUF, KB, S) do {                                                                   \
    const int krow = (KB) * 16 + lq;                                                          \
    bf16x8 ak0 = *(const bf16x8*)&Ks[BUF][krow * 64 + ((quad) ^ (lq & 7)) * 8];               \
    bf16x8 ak1 = *(const bf16x8*)&Ks[BUF][krow * 64 + ((4 + quad) ^ (lq & 7)) * 8];           \
    S = mfma_k32(ak0, qa0, (f32x4){0.f, 0.f, 0.f, 0.f});                                      \
    S = mfma_k32(ak1, qa1, S);                                                                \
} while (0)

#define SMB(S, P, PF) do {                                       \
    float p0 = exp2f(fmaf((P).x, LOG2E, (S)[0]));                \
    float p1 = exp2f(fmaf((P).y, LOG2E, (S)[1]));                \
    float p2 = exp2f(fmaf((P).z, LOG2E, (S)[2]));                \
    float p3 = exp2f(fmaf((P).w, LOG2E, (S)[3]));                \
    (PF).h[0] = (bf16)p0; (PF).h[1] = (bf16)p1;                  \
    (PF).h[2] = (bf16)p2; (PF).h[3] = (bf16)p3;                  \
} while (0)

#define BODY(IT, BUF) do {                                                                     \
    if ((IT) + 1 < NT) STAGE(((IT) + 1) * 64, (BUF) ^ 1);                                      \
    const int pbn = ((IT) + 1) * 16 + quad;                                                    \
    B4 pf[4];                                                                                  \
    f32x4 s0, s1, s2, s3;                                                                      \
    __builtin_amdgcn_s_setprio(1);                                                             \
    QK(BUF, 0, s0);                                                                            \
    QK(BUF, 1, s1);                                                                            \
    SMB(s0, pA0, pf[0]); if ((IT) + 1 < NT) pA0 = pos4[pbn];                                   \
    QK(BUF, 2, s2);                                                                            \
    SMB(s1, pA1, pf[1]); if ((IT) + 1 < NT) pA1 = pos4[pbn + 4];                               \
    QK(BUF, 3, s3);                                                                            \
    SMB(s2, pA2, pf[2]); if ((IT) + 1 < NT) pA2 = pos4[pbn + 8];                               \
    SMB(s3, pA3, pf[3]); if ((IT) + 1 < NT) pA3 = pos4[pbn + 12];                              \
    _Pragma("unroll")                                                                          \
    for (int kb = 0; kb < 4; kb++)                                                             \
        o_l = mfma_k16(onesb.s, pf[kb].s, o_l);                                                \
    _Pragma("unroll")                                                                          \
    for (int db = 0; db < 4; db++) {                                                           \
        const int vrow = db * 16 + lq;                                                         \
        _Pragma("unroll")                                                                      \
        for (int kb = 0; kb < 4; kb++) {                                                       \
            s16x4 va = *(const s16x4*)&Vs[BUF][vrow * 64                                       \
                          + (((kb * 2 + (quad >> 1)) ^ (lq & 7)) * 8) + (quad & 1) * 4];       \
            o_acc[db] = mfma_k16(va, pf[kb].s, o_acc[db]);                                     \
        }                                                                                      \
    }                                                                                          \
    __builtin_amdgcn_s_setprio(0);                                                             \
    if ((IT) + 1 < NT) {                                                                       \
        WAIT_VMCNT(4);                 /* own K/V DMAs done; pos stays in flight */            \
        __builtin_amdgcn_s_barrier();  /* publish tile to all waves */                         \
        code_fence();                  /* next ds_reads must not hoist above */                \
    }                                                                                          \
} while (0)

    for (int it2 = 0; it2 < NT; it2 += 2) {
        BODY(it2,     0);
        BODY(it2 + 1, 1);
    }
#undef BODY
#undef SMB
#undef QK
#undef STAGE

    // o_l holds the full row denominator (summed across all quads by the MFMA)
    float inv = 1.f / o_l[0];
    const size_t orow = (size_t)(b * LQ + q0 + w * 16 + lq) * DIM + h * HDIM;
    #pragma unroll
    for (int dblk = 0; dblk < 4; dblk++) {
        B4 ob;
        #pragma unroll
        for (int r = 0; r < 4; r++) ob.h[r] = (bf16)(o_acc[dblk][r] * inv);
        *(s16x4*)&O[orow + dblk * 16 + quad * 4] = ob.s;
    }
}

// ---------------- host ----------------
extern "C" void kernel_launch(void* const* d_in, const int* in_sizes, int n_in,
                              void* d_out, int out_size, void* d_ws, size_t ws_size,
                              hipStream_t stream) {
    const float* q     = (const float*)d_in[0];
    const float* kv    = (const float*)d_in[1];
    const float* pos   = (const float*)d_in[2];
    const float* Wq    = (const float*)d_in[3];
    const float* Wkv   = (const float*)d_in[4];
    const float* Wproj = (const float*)d_in[5];
    const float* bproj = (const float*)d_in[6];
    float* out = (float*)d_out;

    char* ws = (char*)d_ws;
    size_t off = 0;
    auto alloc = [&](size_t bytes) -> void* {
        void* p = ws + off;
        off += (bytes + 255) & ~(size_t)255;
        return p;
    };

    const int M = BATCH * LQ;
    bf16* qb   = (bf16*)alloc((size_t)M * DIM * 2);
    bf16* kvb  = (bf16*)alloc((size_t)M * DIM * 2);
    bf16* wall = (bf16*)alloc((size_t)3 * DIM * DIM * 2);
    bf16* wpb  = (bf16*)alloc((size_t)DIM * DIM * 2);
    bf16* Qp   = (bf16*)alloc((size_t)M * DIM * 2);
    bf16* Kp   = (bf16*)alloc((size_t)M * DIM * 2);
    bf16* Vt   = (bf16*)alloc((size_t)BATCH * NHEADS * HDIM * LKV * 2);
    bf16* Ob   = (bf16*)alloc((size_t)M * DIM * 2);

    {
        int total = 2 * NQ4 + 4 * NW4;
        cvt_all<<<(total + 255) / 256, 256, 0, stream>>>(
            (const float4*)q, (const float4*)kv, (const float4*)Wq,
            (const float4*)Wkv, (const float4*)Wproj,
            (bf16x4*)qb, (bf16x4*)kvb, (bf16x4*)wall, (bf16x4*)wpb);
    }

    proj_gemm<<<dim3(M / 128, (3 * DIM) / 128), 256, 0, stream>>>(qb, kvb, wall, Qp, Kp, Vt);
    attn_kernel<<<dim3((LQ / 64) * NHEADS * BATCH), 256, 0, stream>>>(Qp, Kp, Vt, pos, Ob);
    out_gemm<<<dim3(M / 64, DIM / 128), 256, 0, stream>>>(Ob, wpb, out, bproj, M, DIM, DIM);
}

// Round 7
// 286.856 us; speedup vs baseline: 1.0039x; 1.0039x over previous
//
#include <hip/hip_runtime.h>

#define DIM 768
#define NHEADS 12
#define HDIM 64
#define BATCH 8
#define LQ 1024
#define LKV 1024
#define ATTN_SCALE 0.125f
#define LOG2E 1.4426950408889634f
// ATTN_SCALE * LOG2E, pre-applied to Q in proj_gemm's epilogue.
#define C1_SL2E 0.18033688011112042f

typedef __bf16 bf16;
typedef __bf16 bf16x4 __attribute__((ext_vector_type(4)));
typedef __bf16 bf16x8 __attribute__((ext_vector_type(8)));
typedef short s16x4 __attribute__((ext_vector_type(4)));
typedef float f32x4 __attribute__((ext_vector_type(4)));

union B4 { bf16x4 h; s16x4 s; };

static __device__ __forceinline__ f32x4 mfma_k32(bf16x8 a, bf16x8 b, f32x4 c) {
    return __builtin_amdgcn_mfma_f32_16x16x32_bf16(a, b, c, 0, 0, 0);
}
static __device__ __forceinline__ f32x4 mfma_k16(s16x4 a, s16x4 b, f32x4 c) {
    return __builtin_amdgcn_mfma_f32_16x16x16bf16_1k(a, b, c, 0, 0, 0);
}

static __device__ __forceinline__ void async16(const bf16* g, bf16* l) {
    __builtin_amdgcn_global_load_lds(
        (const __attribute__((address_space(1))) unsigned int*)g,
        (__attribute__((address_space(3))) unsigned int*)l, 16, 0, 0);
}
static __device__ __forceinline__ void drain_vmem() {
    __asm__ volatile("s_waitcnt vmcnt(0)" ::: "memory");
}
// counted wait: leave the newest N vmem ops (pos prefetch) in flight
#define WAIT_VMCNT(N) __asm__ volatile("s_waitcnt vmcnt(" #N ")" ::: "memory")
// keep following LDS reads from hoisting above the barrier (rule #18-adjacent)
static __device__ __forceinline__ void code_fence() {
    __asm__ volatile("" ::: "memory");
}

// ---------------- single fused fp32 -> bf16 convert ----------------
#define NQ4 (BATCH * LQ * DIM / 4)
#define NW4 (DIM * DIM / 4)
__global__ void cvt_all(const float4* __restrict__ q, const float4* __restrict__ kv,
                        const float4* __restrict__ Wq, const float4* __restrict__ Wkv,
                        const float4* __restrict__ Wp,
                        bf16x4* __restrict__ qb, bf16x4* __restrict__ kvb,
                        bf16x4* __restrict__ wall, bf16x4* __restrict__ wpb) {
    int i = blockIdx.x * 256 + threadIdx.x;
    const float4* src; bf16x4* dst; int j;
    if (i < NQ4)                { src = q;   dst = qb;        j = i; }
    else if (i < 2 * NQ4)       { src = kv;  dst = kvb;       j = i - NQ4; }
    else if (i < 2 * NQ4 + NW4) { src = Wq;  dst = wall;      j = i - 2 * NQ4; }
    else if (i < 2 * NQ4 + 3 * NW4) { src = Wkv; dst = wall + NW4; j = i - 2 * NQ4 - NW4; }
    else if (i < 2 * NQ4 + 4 * NW4) { src = Wp;  dst = wpb;   j = i - 2 * NQ4 - 3 * NW4; }
    else return;
    float4 v = src[j];
    bf16x4 o;
    o[0] = (bf16)v.x; o[1] = (bf16)v.y; o[2] = (bf16)v.z; o[3] = (bf16)v.w;
    dst[j] = o;
}

// ---------------- fused projection GEMM (round-2 proven serial structure) ----------------
// Q output is pre-scaled by ATTN_SCALE*LOG2E so the attn softmax exponent is a
// single fma: e = fmaf(pos, LOG2E, s_prescaled).
__global__ __launch_bounds__(256) void proj_gemm(
    const bf16* __restrict__ qb, const bf16* __restrict__ kvb,
    const bf16* __restrict__ W,
    bf16* __restrict__ Qp, bf16* __restrict__ Kp, bf16* __restrict__ Vt)
{
    __shared__ bf16 As[128 * 32];
    __shared__ bf16 Bs[128 * 32];
    const int tid  = threadIdx.x;
    const int lane = tid & 63;
    const int w    = tid >> 6;
    const int wm = (w >> 1) * 64;
    const int wn = (w & 1) * 64;
    const int m0 = blockIdx.x * 128;
    const int n0 = blockIdx.y * 128;
    const int K = DIM;
    const int lq = lane & 15;
    const int quad = lane >> 4;

    const bf16* A = (n0 < DIM) ? qb : kvb;
    const int isV = (n0 >= 2 * DIM);

    const int rl = lane >> 2;
    const int ck = (lane & 3) * 8;
    const bf16* gA = A + (size_t)(m0 + w * 32 + rl) * K + ck;
    const bf16* gB = W + (size_t)(n0 + w * 32 + rl) * K + ck;
    bf16* lA = &As[w * 1024];
    bf16* lB = &Bs[w * 1024];

    f32x4 acc[4][4] = {};

    for (int k0 = 0; k0 < K; k0 += 32) {
        async16(gA + k0,                  lA);
        async16(gA + (size_t)16 * K + k0, lA + 512);
        async16(gB + k0,                  lB);
        async16(gB + (size_t)16 * K + k0, lB + 512);
        drain_vmem();
        __syncthreads();

        bf16x8 a[4], b[4];
        #pragma unroll
        for (int i = 0; i < 4; i++)
            a[i] = *(const bf16x8*)&As[(wm + i * 16 + lq) * 32 + quad * 8];
        #pragma unroll
        for (int j = 0; j < 4; j++)
            b[j] = *(const bf16x8*)&Bs[(wn + j * 16 + lq) * 32 + quad * 8];
        if (isV) {
            #pragma unroll
            for (int i = 0; i < 4; i++)
                #pragma unroll
                for (int j = 0; j < 4; j++)
                    acc[i][j] = mfma_k32(a[i], b[j], acc[i][j]);
        } else {
            #pragma unroll
            for (int i = 0; i < 4; i++)
                #pragma unroll
                for (int j = 0; j < 4; j++)
                    acc[i][j] = mfma_k32(b[j], a[i], acc[i][j]);
        }
        __syncthreads();
    }

    if (isV) {
        const int n0v = n0 - 2 * DIM;
        #pragma unroll
        for (int i = 0; i < 4; i++) {
            const int base_m = m0 + wm + i * 16;
            const int b_idx = base_m >> 10;
            const int kvl = (base_m & 1023) + quad * 4;
            #pragma unroll
            for (int j = 0; j < 4; j++) {
                const int nl = n0v + wn + j * 16 + lq;
                const int h = nl >> 6;
                const int d = nl & 63;
                B4 pk;
                #pragma unroll
                for (int r = 0; r < 4; r++) pk.h[r] = (bf16)acc[i][j][r];
                *(s16x4*)&Vt[(((size_t)b_idx * NHEADS + h) * HDIM + d) * LKV + kvl] = pk.s;
            }
        }
    } else {
        bf16* Cb = (n0 < DIM) ? Qp : Kp;
        const float cs = (n0 < DIM) ? C1_SL2E : 1.0f;   // pre-scale Q only
        const int nb = (n0 < DIM) ? n0 : n0 - DIM;
        #pragma unroll
        for (int i = 0; i < 4; i++) {
            const size_t row = m0 + wm + i * 16 + lq;
            #pragma unroll
            for (int j = 0; j < 4; j++) {
                const int col = nb + wn + j * 16 + quad * 4;
                B4 pk;
                #pragma unroll
                for (int r = 0; r < 4; r++) pk.h[r] = (bf16)(acc[i][j][r] * cs);
                *(s16x4*)&Cb[row * DIM + col] = pk.s;
            }
        }
    }
}

// ---------------- final GEMM: 64x128 tiles (round-2 proven serial structure) ----------------
__global__ __launch_bounds__(256) void out_gemm(
    const bf16* __restrict__ A, const bf16* __restrict__ B,
    float* __restrict__ Cp, const float* __restrict__ bias, int M, int N, int K)
{
    __shared__ bf16 As[64 * 32];
    __shared__ bf16 Bs[128 * 32];
    const int tid  = threadIdx.x;
    const int lane = tid & 63;
    const int w    = tid >> 6;
    const int wm = (w >> 1) * 32;
    const int wn = (w & 1) * 64;
    const int m0 = blockIdx.x * 64;
    const int n0 = blockIdx.y * 128;
    const int lq = lane & 15;
    const int quad = lane >> 4;

    const int rl = lane >> 2;
    const int ck = (lane & 3) * 8;
    const bf16* gA = A + (size_t)(m0 + w * 16 + rl) * K + ck;
    const bf16* gB = B + (size_t)(n0 + w * 32 + rl) * K + ck;
    bf16* lA = &As[w * 512];
    bf16* lB = &Bs[w * 1024];

    f32x4 acc[2][4] = {};

    for (int k0 = 0; k0 < K; k0 += 32) {
        async16(gA + k0,                  lA);
        async16(gB + k0,                  lB);
        async16(gB + (size_t)16 * K + k0, lB + 512);
        drain_vmem();
        __syncthreads();

        bf16x8 a[2], b[4];
        #pragma unroll
        for (int i = 0; i < 2; i++)
            a[i] = *(const bf16x8*)&As[(wm + i * 16 + lq) * 32 + quad * 8];
        #pragma unroll
        for (int j = 0; j < 4; j++)
            b[j] = *(const bf16x8*)&Bs[(wn + j * 16 + lq) * 32 + quad * 8];
        #pragma unroll
        for (int i = 0; i < 2; i++)
            #pragma unroll
            for (int j = 0; j < 4; j++)
                acc[i][j] = mfma_k32(b[j], a[i], acc[i][j]);
        __syncthreads();
    }

    #pragma unroll
    for (int i = 0; i < 2; i++) {
        const size_t row = m0 + wm + i * 16 + lq;
        #pragma unroll
        for (int j = 0; j < 4; j++) {
            const int col = n0 + wn + j * 16 + quad * 4;
            float4 bj = *(const float4*)&bias[col];
            float4 o;
            o.x = acc[i][j][0] + bj.x; o.y = acc[i][j][1] + bj.y;
            o.z = acc[i][j][2] + bj.z; o.w = acc[i][j][3] + bj.w;
            *(float4*)&Cp[row * N + col] = o;
        }
    }
}

// ---------------- fused attention: QBLK=128, 8 waves ----------------
// Round-7 structural change. Round-6 evidence: removing 25% of VALU work moved
// time only 87->85.7 us; no pipe >45% busy; issue-work ~8x below wall time ->
// latency/sync-bound, not throughput-bound. Fix arithmetic intensity: each
// staged 64-kv K/V tile now feeds 128 q-rows (8 waves) instead of 64 (4 waves):
//  * K/V DMA traffic and issue per CU halved (2 async16/thread, 512 threads)
//  * barriers per unit MFMA work halved
//  * grid 768 blocks = 3 blocks/CU, ALL co-resident (24 waves/CU, VGPR-capped);
//    zero dispatch churn, no tail
// Per-wave inner body is identical to round 6 (verified): raw s_barrier +
// vmcnt(4) (2 staging DMAs oldest, 4 pos loads newest -> vmcnt(4) drains just
// the DMAs), depth-1 pos prefetch in named regs, MFMA-ones denominator,
// QK/softmax interleave, setprio, source-side XOR-swizzled staging.
// XCD remap for 768 blocks: c=i&7 (XCD), b=(i>>3)&7, u=i>>6 in [0,12);
// g = c*12+u in [0,96): h=g>>3, q0=(g&7)*128. Same-(h,q0) blocks (8 b's) share
// c -> same XCD within a 64-id window -> pos tile fetched once per XCD.
__global__ __launch_bounds__(512) void attn_kernel(
    const bf16* __restrict__ Qb,   // (B*LQ, 768), Q cols pre-scaled
    const bf16* __restrict__ Kb,   // (B*LKV, 768)
    const bf16* __restrict__ Vt,   // (B*H*64, LKV)
    const float* __restrict__ pos, // (H, LQ, LKV)
    bf16* __restrict__ O)          // (B*LQ, 768)
{
    __shared__ bf16 Ks[2][64 * 64];   // [buf][kv][d]  128B rows, source-swizzled
    __shared__ bf16 Vs[2][64 * 64];   // [buf][d][kv]  128B rows, source-swizzled

    const int i  = blockIdx.x;
    const int g  = (i & 7) * 12 + (i >> 6);    // (h,q0-tile) group, XCD-resident
    const int b  = (i >> 3) & 7;
    const int h  = g >> 3;
    const int q0 = (g & 7) * 128;
    const int bh = b * NHEADS + h;
    const int t = threadIdx.x;
    const int lane = t & 63;
    const int w = t >> 6;                      // 0..7 -> q-rows q0 + w*16 + lq
    const int lq = lane & 15;
    const int quad = lane >> 4;

    const bf16* qg = Qb + (size_t)(b * LQ + q0 + w * 16 + lq) * DIM + h * HDIM + quad * 8;
    bf16x8 qa0 = *(const bf16x8*)(qg);
    bf16x8 qa1 = *(const bf16x8*)(qg + 32);

    // staging: 512 threads cover 64 rows x 8 chunks; 2 DMAs per thread (K,V)
    const int srow  = t >> 3;                      // 0..63
    const int chunk = t & 7;
    const int sw    = (chunk ^ (srow & 7)) * 8;    // swizzled global-source offset
    const bf16* Kg = Kb + (size_t)(b * LKV + srow) * DIM + h * HDIM + sw;
    const bf16* Vg = Vt + (size_t)(bh * HDIM + srow) * LKV + sw;

#define STAGE(kv0, bufi) do {                                                 \
    async16(Kg + (size_t)(kv0) * DIM, &Ks[bufi][srow * 64 + chunk * 8]);      \
    async16(Vg + (kv0),               &Vs[bufi][srow * 64 + chunk * 8]);      \
} while (0)

#define NT (LKV / 64)

    const float4* pos4 = (const float4*)(pos + ((size_t)h * LQ + q0 + w * 16 + lq) * LKV);

    // MFMA-ones operand: 4x bf16(1.0) = 0x3F80
    B4 onesb;
    onesb.s = (s16x4){0x3F80, 0x3F80, 0x3F80, 0x3F80};

    f32x4 o_acc[4] = {};
    f32x4 o_l = {};

    // prologue: tile0 DMA first (oldest), then pos(0) prefetch
    STAGE(0, 0);
    float4 pA0 = pos4[quad],      pA1 = pos4[4 + quad];
    float4 pA2 = pos4[8 + quad],  pA3 = pos4[12 + quad];
    WAIT_VMCNT(4);                     // 2 DMAs done; 4 pos loads stay in flight
    __builtin_amdgcn_s_barrier();
    code_fence();

#define QK(BUF, KB, S) do {                                                                   \
    const int krow = (KB) * 16 + lq;                                                          \
    bf16x8 ak0 = *(const bf16x8*)&Ks[BUF][krow * 64 + ((quad) ^ (lq & 7)) * 8];               \
    bf16x8 ak1 = *(const bf16x8*)&Ks[BUF][krow * 64 + ((4 + quad) ^ (lq & 7)) * 8];           \
    S = mfma_k32(ak0, qa0, (f32x4){0.f, 0.f, 0.f, 0.f});                                      \
    S = mfma_k32(ak1, qa1, S);                                                                \
} while (0)

#define SMB(S, P, PF) do {                                       \
    float p0 = exp2f(fmaf((P).x, LOG2E, (S)[0]));                \
    float p1 = exp2f(fmaf((P).y, LOG2E, (S)[1]));                \
    float p2 = exp2f(fmaf((P).z, LOG2E, (S)[2]));                \
    float p3 = exp2f(fmaf((P).w, LOG2E, (S)[3]));                \
    (PF).h[0] = (bf16)p0; (PF).h[1] = (bf16)p1;                  \
    (PF).h[2] = (bf16)p2; (PF).h[3] = (bf16)p3;                  \
} while (0)

#define BODY(IT, BUF) do {                                                                     \
    if ((IT) + 1 < NT) STAGE(((IT) + 1) * 64, (BUF) ^ 1);                                      \
    const int pbn = ((IT) + 1) * 16 + quad;                                                    \
    B4 pf[4];                                                                                  \
    f32x4 s0, s1, s2, s3;                                                                      \
    __builtin_amdgcn_s_setprio(1);                                                             \
    QK(BUF, 0, s0);                                                                            \
    QK(BUF, 1, s1);                                                                            \
    SMB(s0, pA0, pf[0]); if ((IT) + 1 < NT) pA0 = pos4[pbn];                                   \
    QK(BUF, 2, s2);                                                                            \
    SMB(s1, pA1, pf[1]); if ((IT) + 1 < NT) pA1 = pos4[pbn + 4];                               \
    QK(BUF, 3, s3);                                                                            \
    SMB(s2, pA2, pf[2]); if ((IT) + 1 < NT) pA2 = pos4[pbn + 8];                               \
    SMB(s3, pA3, pf[3]); if ((IT) + 1 < NT) pA3 = pos4[pbn + 12];                              \
    _Pragma("unroll")                                                                          \
    for (int kb = 0; kb < 4; kb++)                                                             \
        o_l = mfma_k16(onesb.s, pf[kb].s, o_l);                                                \
    _Pragma("unroll")                                                                          \
    for (int db = 0; db < 4; db++) {                                                           \
        const int vrow = db * 16 + lq;                                                         \
        _Pragma("unroll")                                                                      \
        for (int kb = 0; kb < 4; kb++) {                                                       \
            s16x4 va = *(const s16x4*)&Vs[BUF][vrow * 64                                       \
                          + (((kb * 2 + (quad >> 1)) ^ (lq & 7)) * 8) + (quad & 1) * 4];       \
            o_acc[db] = mfma_k16(va, pf[kb].s, o_acc[db]);                                     \
        }                                                                                      \
    }                                                                                          \
    __builtin_amdgcn_s_setprio(0);                                                             \
    if ((IT) + 1 < NT) {                                                                       \
        WAIT_VMCNT(4);                 /* own 2 K/V DMAs done; pos stays in flight */          \
        __builtin_amdgcn_s_barrier();  /* publish tile to all waves */                         \
        code_fence();                  /* next ds_reads must not hoist above */                \
    }                                                                                          \
} while (0)

    for (int it2 = 0; it2 < NT; it2 += 2) {
        BODY(it2,     0);
        BODY(it2 + 1, 1);
    }
#undef BODY
#undef SMB
#undef QK
#undef STAGE

    // o_l holds the full row denominator (summed across all quads by the MFMA)
    float inv = 1.f / o_l[0];
    const size_t orow = (size_t)(b * LQ + q0 + w * 16 + lq) * DIM + h * HDIM;
    #pragma unroll
    for (int dblk = 0; dblk < 4; dblk++) {
        B4 ob;
        #pragma unroll
        for (int r = 0; r < 4; r++) ob.h[r] = (bf16)(o_acc[dblk][r] * inv);
        *(s16x4*)&O[orow + dblk * 16 + quad * 4] = ob.s;
    }
}

// ---------------- host ----------------
extern "C" void kernel_launch(void* const* d_in, const int* in_sizes, int n_in,
                              void* d_out, int out_size, void* d_ws, size_t ws_size,
                              hipStream_t stream) {
    const float* q     = (const float*)d_in[0];
    const float* kv    = (const float*)d_in[1];
    const float* pos   = (const float*)d_in[2];
    const float* Wq    = (const float*)d_in[3];
    const float* Wkv   = (const float*)d_in[4];
    const float* Wproj = (const float*)d_in[5];
    const float* bproj = (const float*)d_in[6];
    float* out = (float*)d_out;

    char* ws = (char*)d_ws;
    size_t off = 0;
    auto alloc = [&](size_t bytes) -> void* {
        void* p = ws + off;
        off += (bytes + 255) & ~(size_t)255;
        return p;
    };

    const int M = BATCH * LQ;
    bf16* qb   = (bf16*)alloc((size_t)M * DIM * 2);
    bf16* kvb  = (bf16*)alloc((size_t)M * DIM * 2);
    bf16* wall = (bf16*)alloc((size_t)3 * DIM * DIM * 2);
    bf16* wpb  = (bf16*)alloc((size_t)DIM * DIM * 2);
    bf16* Qp   = (bf16*)alloc((size_t)M * DIM * 2);
    bf16* Kp   = (bf16*)alloc((size_t)M * DIM * 2);
    bf16* Vt   = (bf16*)alloc((size_t)BATCH * NHEADS * HDIM * LKV * 2);
    bf16* Ob   = (bf16*)alloc((size_t)M * DIM * 2);

    {
        int total = 2 * NQ4 + 4 * NW4;
        cvt_all<<<(total + 255) / 256, 256, 0, stream>>>(
            (const float4*)q, (const float4*)kv, (const float4*)Wq,
            (const float4*)Wkv, (const float4*)Wproj,
            (bf16x4*)qb, (bf16x4*)kvb, (bf16x4*)wall, (bf16x4*)wpb);
    }

    proj_gemm<<<dim3(M / 128, (3 * DIM) / 128), 256, 0, stream>>>(qb, kvb, wall, Qp, Kp, Vt);
    attn_kernel<<<dim3((LQ / 128) * NHEADS * BATCH), 512, 0, stream>>>(Qp, Kp, Vt, pos, Ob);
    out_gemm<<<dim3(M / 64, DIM / 128), 256, 0, stream>>>(Ob, wpb, out, bproj, M, DIM, DIM);
}

// Round 9
// 269.204 us; speedup vs baseline: 1.0698x; 1.0656x over previous
//
#include <hip/hip_runtime.h>

#define DIM 768
#define NHEADS 12
#define HDIM 64
#define BATCH 8
#define LQ 1024
#define LKV 1024
#define ATTN_SCALE 0.125f
#define LOG2E 1.4426950408889634f
// ATTN_SCALE * LOG2E, pre-applied to Q in proj_gemm's epilogue.
#define C1_SL2E 0.18033688011112042f

typedef __bf16 bf16;
typedef __bf16 bf16x4 __attribute__((ext_vector_type(4)));
typedef __bf16 bf16x8 __attribute__((ext_vector_type(8)));
typedef short s16x4 __attribute__((ext_vector_type(4)));
typedef float f32x4 __attribute__((ext_vector_type(4)));

union B4 { bf16x4 h; s16x4 s; };

static __device__ __forceinline__ f32x4 mfma_k32(bf16x8 a, bf16x8 b, f32x4 c) {
    return __builtin_amdgcn_mfma_f32_16x16x32_bf16(a, b, c, 0, 0, 0);
}
static __device__ __forceinline__ f32x4 mfma_k16(s16x4 a, s16x4 b, f32x4 c) {
    return __builtin_amdgcn_mfma_f32_16x16x16bf16_1k(a, b, c, 0, 0, 0);
}

static __device__ __forceinline__ void async16(const bf16* g, bf16* l) {
    __builtin_amdgcn_global_load_lds(
        (const __attribute__((address_space(1))) unsigned int*)g,
        (__attribute__((address_space(3))) unsigned int*)l, 16, 0, 0);
}
static __device__ __forceinline__ void drain_vmem() {
    __asm__ volatile("s_waitcnt vmcnt(0)" ::: "memory");
}
// counted wait: leave the newest N vmem ops (pos prefetch) in flight
#define WAIT_VMCNT(N) __asm__ volatile("s_waitcnt vmcnt(" #N ")" ::: "memory")
// keep following LDS reads from hoisting above the barrier (rule #18-adjacent)
static __device__ __forceinline__ void code_fence() {
    __asm__ volatile("" ::: "memory");
}

// ---------------- single fused fp32 -> bf16 convert ----------------
#define NQ4 (BATCH * LQ * DIM / 4)
#define NW4 (DIM * DIM / 4)
__global__ void cvt_all(const float4* __restrict__ q, const float4* __restrict__ kv,
                        const float4* __restrict__ Wq, const float4* __restrict__ Wkv,
                        const float4* __restrict__ Wp,
                        bf16x4* __restrict__ qb, bf16x4* __restrict__ kvb,
                        bf16x4* __restrict__ wall, bf16x4* __restrict__ wpb) {
    int i = blockIdx.x * 256 + threadIdx.x;
    const float4* src; bf16x4* dst; int j;
    if (i < NQ4)                { src = q;   dst = qb;        j = i; }
    else if (i < 2 * NQ4)       { src = kv;  dst = kvb;       j = i - NQ4; }
    else if (i < 2 * NQ4 + NW4) { src = Wq;  dst = wall;      j = i - 2 * NQ4; }
    else if (i < 2 * NQ4 + 3 * NW4) { src = Wkv; dst = wall + NW4; j = i - 2 * NQ4 - NW4; }
    else if (i < 2 * NQ4 + 4 * NW4) { src = Wp;  dst = wpb;   j = i - 2 * NQ4 - 3 * NW4; }
    else return;
    float4 v = src[j];
    bf16x4 o;
    o[0] = (bf16)v.x; o[1] = (bf16)v.y; o[2] = (bf16)v.z; o[3] = (bf16)v.w;
    dst[j] = o;
}

// ---------------- fused projection GEMM: BK=64, swizzled staging ----------------
// Round-9 = round-8 resubmission (infra failure, kernel re-audited clean).
// BK 32->64 halves the barrier count (24->12 per block); LDS rows are 128B with
// the attn XOR swizzle (LDS slot `c` of row r holds global chunk c^(r&7); reads
// use the same XOR) -> fragment ds_read_b128 conflict-free (old [row][32]
// layout was ~8-way). LDS 32KB -> 5 blocks/CU. Q pre-scaled by ATTN_SCALE*LOG2E.
__global__ __launch_bounds__(256) void proj_gemm(
    const bf16* __restrict__ qb, const bf16* __restrict__ kvb,
    const bf16* __restrict__ W,
    bf16* __restrict__ Qp, bf16* __restrict__ Kp, bf16* __restrict__ Vt)
{
    __shared__ bf16 As[128 * 64];   // 16KB, [row][slot], slot = chunk^(row&7)
    __shared__ bf16 Bs[128 * 64];   // 16KB
    const int tid  = threadIdx.x;
    const int lane = tid & 63;
    const int w    = tid >> 6;
    const int wm = (w >> 1) * 64;
    const int wn = (w & 1) * 64;
    const int m0 = blockIdx.x * 128;
    const int n0 = blockIdx.y * 128;
    const int K = DIM;
    const int lq = lane & 15;
    const int quad = lane >> 4;

    const bf16* A = (n0 < DIM) ? qb : kvb;
    const int isV = (n0 >= 2 * DIM);

    // staging: wave w covers rows w*32+p*8+rl8 (p=0..3); lane covers chunk `ch`
    // of a 128B row. dest row&7 == rl8 (p*8, w*32 are 0 mod 8) -> source swizzle
    // by rl8 matches dest-row swizzle. LDS dest is linear in lane (base+l*16).
    const int rl8 = lane >> 3;                  // 0..7
    const int ch  = lane & 7;                   // 16B chunk
    const int swc = (ch ^ rl8) * 8;             // swizzled global elem offset
    const bf16* gA = A + (size_t)(m0 + w * 32 + rl8) * K + swc;
    const bf16* gB = W + (size_t)(n0 + w * 32 + rl8) * K + swc;
    bf16* lA = &As[w * 2048];                   // 32 rows * 64 elems
    bf16* lB = &Bs[w * 2048];

    f32x4 acc[4][4] = {};

    for (int k0 = 0; k0 < K; k0 += 64) {
        #pragma unroll
        for (int p = 0; p < 4; p++) {
            async16(gA + (size_t)(p * 8) * K + k0, lA + p * 512);
            async16(gB + (size_t)(p * 8) * K + k0, lB + p * 512);
        }
        drain_vmem();
        __syncthreads();

        #pragma unroll
        for (int ki = 0; ki < 2; ki++) {
            bf16x8 a[4], b[4];
            #pragma unroll
            for (int i = 0; i < 4; i++) {
                const int ra = wm + i * 16 + lq;
                a[i] = *(const bf16x8*)&As[ra * 64 + (((ki * 4 + quad) ^ (lq & 7)) * 8)];
            }
            #pragma unroll
            for (int j = 0; j < 4; j++) {
                const int rb = wn + j * 16 + lq;
                b[j] = *(const bf16x8*)&Bs[rb * 64 + (((ki * 4 + quad) ^ (lq & 7)) * 8)];
            }
            if (isV) {
                #pragma unroll
                for (int i = 0; i < 4; i++)
                    #pragma unroll
                    for (int j = 0; j < 4; j++)
                        acc[i][j] = mfma_k32(a[i], b[j], acc[i][j]);
            } else {
                #pragma unroll
                for (int i = 0; i < 4; i++)
                    #pragma unroll
                    for (int j = 0; j < 4; j++)
                        acc[i][j] = mfma_k32(b[j], a[i], acc[i][j]);
            }
        }
        __syncthreads();
    }

    if (isV) {
        const int n0v = n0 - 2 * DIM;
        #pragma unroll
        for (int i = 0; i < 4; i++) {
            const int base_m = m0 + wm + i * 16;
            const int b_idx = base_m >> 10;
            const int kvl = (base_m & 1023) + quad * 4;
            #pragma unroll
            for (int j = 0; j < 4; j++) {
                const int nl = n0v + wn + j * 16 + lq;
                const int h = nl >> 6;
                const int d = nl & 63;
                B4 pk;
                #pragma unroll
                for (int r = 0; r < 4; r++) pk.h[r] = (bf16)acc[i][j][r];
                *(s16x4*)&Vt[(((size_t)b_idx * NHEADS + h) * HDIM + d) * LKV + kvl] = pk.s;
            }
        }
    } else {
        bf16* Cb = (n0 < DIM) ? Qp : Kp;
        const float cs = (n0 < DIM) ? C1_SL2E : 1.0f;   // pre-scale Q only
        const int nb = (n0 < DIM) ? n0 : n0 - DIM;
        #pragma unroll
        for (int i = 0; i < 4; i++) {
            const size_t row = m0 + wm + i * 16 + lq;
            #pragma unroll
            for (int j = 0; j < 4; j++) {
                const int col = nb + wn + j * 16 + quad * 4;
                B4 pk;
                #pragma unroll
                for (int r = 0; r < 4; r++) pk.h[r] = (bf16)(acc[i][j][r] * cs);
                *(s16x4*)&Cb[row * DIM + col] = pk.s;
            }
        }
    }
}

// ---------------- final GEMM: 64x128 tiles, BK=64, swizzled staging ----------------
__global__ __launch_bounds__(256) void out_gemm(
    const bf16* __restrict__ A, const bf16* __restrict__ B,
    float* __restrict__ Cp, const float* __restrict__ bias, int M, int N, int K)
{
    __shared__ bf16 As[64 * 64];    // 8KB
    __shared__ bf16 Bs[128 * 64];   // 16KB
    const int tid  = threadIdx.x;
    const int lane = tid & 63;
    const int w    = tid >> 6;
    const int wm = (w >> 1) * 32;
    const int wn = (w & 1) * 64;
    const int m0 = blockIdx.x * 64;
    const int n0 = blockIdx.y * 128;
    const int lq = lane & 15;
    const int quad = lane >> 4;

    const int rl8 = lane >> 3;
    const int ch  = lane & 7;
    const int swc = (ch ^ rl8) * 8;
    const bf16* gA = A + (size_t)(m0 + w * 16 + rl8) * K + swc;
    const bf16* gB = B + (size_t)(n0 + w * 32 + rl8) * K + swc;
    bf16* lA = &As[w * 1024];       // 16 rows * 64
    bf16* lB = &Bs[w * 2048];       // 32 rows * 64

    f32x4 acc[2][4] = {};

    for (int k0 = 0; k0 < K; k0 += 64) {
        #pragma unroll
        for (int p = 0; p < 2; p++)
            async16(gA + (size_t)(p * 8) * K + k0, lA + p * 512);
        #pragma unroll
        for (int p = 0; p < 4; p++)
            async16(gB + (size_t)(p * 8) * K + k0, lB + p * 512);
        drain_vmem();
        __syncthreads();

        #pragma unroll
        for (int ki = 0; ki < 2; ki++) {
            bf16x8 a[2], b[4];
            #pragma unroll
            for (int i = 0; i < 2; i++) {
                const int ra = wm + i * 16 + lq;
                a[i] = *(const bf16x8*)&As[ra * 64 + (((ki * 4 + quad) ^ (lq & 7)) * 8)];
            }
            #pragma unroll
            for (int j = 0; j < 4; j++) {
                const int rb = wn + j * 16 + lq;
                b[j] = *(const bf16x8*)&Bs[rb * 64 + (((ki * 4 + quad) ^ (lq & 7)) * 8)];
            }
            #pragma unroll
            for (int i = 0; i < 2; i++)
                #pragma unroll
                for (int j = 0; j < 4; j++)
                    acc[i][j] = mfma_k32(b[j], a[i], acc[i][j]);
        }
        __syncthreads();
    }

    #pragma unroll
    for (int i = 0; i < 2; i++) {
        const size_t row = m0 + wm + i * 16 + lq;
        #pragma unroll
        for (int j = 0; j < 4; j++) {
            const int col = n0 + wn + j * 16 + quad * 4;
            float4 bj = *(const float4*)&bias[col];
            float4 o;
            o.x = acc[i][j][0] + bj.x; o.y = acc[i][j][1] + bj.y;
            o.z = acc[i][j][2] + bj.z; o.w = acc[i][j][3] + bj.w;
            *(float4*)&Cp[row * N + col] = o;
        }
    }
}

// ---------------- fused attention: QBLK=128, 8 waves (round-7, unchanged) ----------------
// Kept byte-identical this round as the experiment CONTROL: its counters
// (dur ~84us, FETCH ~51MB) should not move; the total delta isolates the GEMMs.
__global__ __launch_bounds__(512) void attn_kernel(
    const bf16* __restrict__ Qb,   // (B*LQ, 768), Q cols pre-scaled
    const bf16* __restrict__ Kb,   // (B*LKV, 768)
    const bf16* __restrict__ Vt,   // (B*H*64, LKV)
    const float* __restrict__ pos, // (H, LQ, LKV)
    bf16* __restrict__ O)          // (B*LQ, 768)
{
    __shared__ bf16 Ks[2][64 * 64];   // [buf][kv][d]  128B rows, source-swizzled
    __shared__ bf16 Vs[2][64 * 64];   // [buf][d][kv]  128B rows, source-swizzled

    const int i  = blockIdx.x;
    const int g  = (i & 7) * 12 + (i >> 6);    // (h,q0-tile) group, XCD-resident
    const int b  = (i >> 3) & 7;
    const int h  = g >> 3;
    const int q0 = (g & 7) * 128;
    const int bh = b * NHEADS + h;
    const int t = threadIdx.x;
    const int lane = t & 63;
    const int w = t >> 6;                      // 0..7 -> q-rows q0 + w*16 + lq
    const int lq = lane & 15;
    const int quad = lane >> 4;

    const bf16* qg = Qb + (size_t)(b * LQ + q0 + w * 16 + lq) * DIM + h * HDIM + quad * 8;
    bf16x8 qa0 = *(const bf16x8*)(qg);
    bf16x8 qa1 = *(const bf16x8*)(qg + 32);

    // staging: 512 threads cover 64 rows x 8 chunks; 2 DMAs per thread (K,V)
    const int srow  = t >> 3;                      // 0..63
    const int chunk = t & 7;
    const int sw    = (chunk ^ (srow & 7)) * 8;    // swizzled global-source offset
    const bf16* Kg = Kb + (size_t)(b * LKV + srow) * DIM + h * HDIM + sw;
    const bf16* Vg = Vt + (size_t)(bh * HDIM + srow) * LKV + sw;

#define STAGE(kv0, bufi) do {                                                 \
    async16(Kg + (size_t)(kv0) * DIM, &Ks[bufi][srow * 64 + chunk * 8]);      \
    async16(Vg + (kv0),               &Vs[bufi][srow * 64 + chunk * 8]);      \
} while (0)

#define NT (LKV / 64)

    const float4* pos4 = (const float4*)(pos + ((size_t)h * LQ + q0 + w * 16 + lq) * LKV);

    // MFMA-ones operand: 4x bf16(1.0) = 0x3F80
    B4 onesb;
    onesb.s = (s16x4){0x3F80, 0x3F80, 0x3F80, 0x3F80};

    f32x4 o_acc[4] = {};
    f32x4 o_l = {};

    // prologue: tile0 DMA first (oldest), then pos(0) prefetch
    STAGE(0, 0);
    float4 pA0 = pos4[quad],      pA1 = pos4[4 + quad];
    float4 pA2 = pos4[8 + quad],  pA3 = pos4[12 + quad];
    WAIT_VMCNT(4);                     // 2 DMAs done; 4 pos loads stay in flight
    __builtin_amdgcn_s_barrier();
    code_fence();

#define QK(BUF, KB, S) do {                                                                   \
    const int krow = (KB) * 16 + lq;                                                          \
    bf16x8 ak0 = *(const bf16x8*)&Ks[BUF][krow * 64 + ((quad) ^ (lq & 7)) * 8];               \
    bf16x8 ak1 = *(const bf16x8*)&Ks[BUF][krow * 64 + ((4 + quad) ^ (lq & 7)) * 8];           \
    S = mfma_k32(ak0, qa0, (f32x4){0.f, 0.f, 0.f, 0.f});                                      \
    S = mfma_k32(ak1, qa1, S);                                                                \
} while (0)

#define SMB(S, P, PF) do {                                       \
    float p0 = exp2f(fmaf((P).x, LOG2E, (S)[0]));                \
    float p1 = exp2f(fmaf((P).y, LOG2E, (S)[1]));                \
    float p2 = exp2f(fmaf((P).z, LOG2E, (S)[2]));                \
    float p3 = exp2f(fmaf((P).w, LOG2E, (S)[3]));                \
    (PF).h[0] = (bf16)p0; (PF).h[1] = (bf16)p1;                  \
    (PF).h[2] = (bf16)p2; (PF).h[3] = (bf16)p3;                  \
} while (0)

#define BODY(IT, BUF) do {                                                                     \
    if ((IT) + 1 < NT) STAGE(((IT) + 1) * 64, (BUF) ^ 1);                                      \
    const int pbn = ((IT) + 1) * 16 + quad;                                                    \
    B4 pf[4];                                                                                  \
    f32x4 s0, s1, s2, s3;                                                                      \
    __builtin_amdgcn_s_setprio(1);                                                             \
    QK(BUF, 0, s0);                                                                            \
    QK(BUF, 1, s1);                                                                            \
    SMB(s0, pA0, pf[0]); if ((IT) + 1 < NT) pA0 = pos4[pbn];                                   \
    QK(BUF, 2, s2);                                                                            \
    SMB(s1, pA1, pf[1]); if ((IT) + 1 < NT) pA1 = pos4[pbn + 4];                               \
    QK(BUF, 3, s3);                                                                            \
    SMB(s2, pA2, pf[2]); if ((IT) + 1 < NT) pA2 = pos4[pbn + 8];                               \
    SMB(s3, pA3, pf[3]); if ((IT) + 1 < NT) pA3 = pos4[pbn + 12];                              \
    _Pragma("unroll")                                                                          \
    for (int kb = 0; kb < 4; kb++)                                                             \
        o_l = mfma_k16(onesb.s, pf[kb].s, o_l);                                                \
    _Pragma("unroll")                                                                          \
    for (int db = 0; db < 4; db++) {                                                           \
        const int vrow = db * 16 + lq;                                                         \
        _Pragma("unroll")                                                                      \
        for (int kb = 0; kb < 4; kb++) {                                                       \
            s16x4 va = *(const s16x4*)&Vs[BUF][vrow * 64                                       \
                          + (((kb * 2 + (quad >> 1)) ^ (lq & 7)) * 8) + (quad & 1) * 4];       \
            o_acc[db] = mfma_k16(va, pf[kb].s, o_acc[db]);                                     \
        }                                                                                      \
    }                                                                                          \
    __builtin_amdgcn_s_setprio(0);                                                             \
    if ((IT) + 1 < NT) {                                                                       \
        WAIT_VMCNT(4);                 /* own 2 K/V DMAs done; pos stays in flight */          \
        __builtin_amdgcn_s_barrier();  /* publish tile to all waves */                         \
        code_fence();                  /* next ds_reads must not hoist above */                \
    }                                                                                          \
} while (0)

    for (int it2 = 0; it2 < NT; it2 += 2) {
        BODY(it2,     0);
        BODY(it2 + 1, 1);
    }
#undef BODY
#undef SMB
#undef QK
#undef STAGE

    // o_l holds the full row denominator (summed across all quads by the MFMA)
    float inv = 1.f / o_l[0];
    const size_t orow = (size_t)(b * LQ + q0 + w * 16 + lq) * DIM + h * HDIM;
    #pragma unroll
    for (int dblk = 0; dblk < 4; dblk++) {
        B4 ob;
        #pragma unroll
        for (int r = 0; r < 4; r++) ob.h[r] = (bf16)(o_acc[dblk][r] * inv);
        *(s16x4*)&O[orow + dblk * 16 + quad * 4] = ob.s;
    }
}

// ---------------- host ----------------
extern "C" void kernel_launch(void* const* d_in, const int* in_sizes, int n_in,
                              void* d_out, int out_size, void* d_ws, size_t ws_size,
                              hipStream_t stream) {
    const float* q     = (const float*)d_in[0];
    const float* kv    = (const float*)d_in[1];
    const float* pos   = (const float*)d_in[2];
    const float* Wq    = (const float*)d_in[3];
    const float* Wkv   = (const float*)d_in[4];
    const float* Wproj = (const float*)d_in[5];
    const float* bproj = (const float*)d_in[6];
    float* out = (float*)d_out;

    char* ws = (char*)d_ws;
    size_t off = 0;
    auto alloc = [&](size_t bytes) -> void* {
        void* p = ws + off;
        off += (bytes + 255) & ~(size_t)255;
        return p;
    };

    const int M = BATCH * LQ;
    bf16* qb   = (bf16*)alloc((size_t)M * DIM * 2);
    bf16* kvb  = (bf16*)alloc((size_t)M * DIM * 2);
    bf16* wall = (bf16*)alloc((size_t)3 * DIM * DIM * 2);
    bf16* wpb  = (bf16*)alloc((size_t)DIM * DIM * 2);
    bf16* Qp   = (bf16*)alloc((size_t)M * DIM * 2);
    bf16* Kp   = (bf16*)alloc((size_t)M * DIM * 2);
    bf16* Vt   = (bf16*)alloc((size_t)BATCH * NHEADS * HDIM * LKV * 2);
    bf16* Ob   = (bf16*)alloc((size_t)M * DIM * 2);

    {
        int total = 2 * NQ4 + 4 * NW4;
        cvt_all<<<(total + 255) / 256, 256, 0, stream>>>(
            (const float4*)q, (const float4*)kv, (const float4*)Wq,
            (const float4*)Wkv, (const float4*)Wproj,
            (bf16x4*)qb, (bf16x4*)kvb, (bf16x4*)wall, (bf16x4*)wpb);
    }

    proj_gemm<<<dim3(M / 128, (3 * DIM) / 128), 256, 0, stream>>>(qb, kvb, wall, Qp, Kp, Vt);
    attn_kernel<<<dim3((LQ / 128) * NHEADS * BATCH), 512, 0, stream>>>(Qp, Kp, Vt, pos, Ob);
    out_gemm<<<dim3(M / 64, DIM / 128), 256, 0, stream>>>(Ob, wpb, out, bproj, M, DIM, DIM);
}